// Round 12
// baseline (818.254 us; speedup 1.0000x reference)
//
#include <hip/hip_runtime.h>

namespace {

constexpr int B = 1024;

using u16 = unsigned short;
using u32 = unsigned int;

typedef __attribute__((ext_vector_type(8))) short bf16x8;
typedef __attribute__((ext_vector_type(4))) float f32x4;

#define MFMA16(a, b, c) __builtin_amdgcn_mfma_f32_16x16x32_bf16(a, b, c, 0, 0, 0)

__device__ __forceinline__ u16 f2bf(float f) {
  u32 u = __builtin_bit_cast(u32, f);
  u += 0x7FFFu + ((u >> 16) & 1u);          // RNE
  return (u16)(u >> 16);
}
__device__ __forceinline__ float bf2f(u16 s) {
  u32 u = ((u32)s) << 16;
  return __builtin_bit_cast(float, u);
}
__device__ __forceinline__ u32 packbf2(float a, float b) {
  return (u32)f2bf(a) | ((u32)f2bf(b) << 16);
}
// truncation split: hi in low16, lo in high16; hi_f + lo_f == f to ~2^-16 rel
__device__ __forceinline__ u32 tsplit(float f) {
  u32 u = __builtin_bit_cast(u32, f);
  float r = f - __builtin_bit_cast(float, u & 0xFFFF0000u);
  u32 ur = __builtin_bit_cast(u32, r);
  return (u >> 16) | (ur & 0xFFFF0000u);
}

// ---------------- K0: fold BN into conv weights (unchanged) ----------------
__global__ __launch_bounds__(256) void k0_fold(
    const float* __restrict__ gg, const float* __restrict__ gbe, const float* __restrict__ gme, const float* __restrict__ gva,
    const float* __restrict__ gw, const float* __restrict__ gbi,
    const float* __restrict__ tg, const float* __restrict__ tbe, const float* __restrict__ tme, const float* __restrict__ tva,
    const float* __restrict__ tw, const float* __restrict__ tbi,
    const float* __restrict__ pg, const float* __restrict__ pbe, const float* __restrict__ pme, const float* __restrict__ pva,
    const float* __restrict__ pw, const float* __restrict__ pbi,
    const float* __restrict__ Ww, const float* __restrict__ Wb,
    const float* __restrict__ Wg2, const float* __restrict__ Wbe, const float* __restrict__ Wme, const float* __restrict__ Wva,
    u16* __restrict__ wgo, float* __restrict__ bgo,
    u16* __restrict__ wthi, u16* __restrict__ wtlo, float* __restrict__ bto,
    u16* __restrict__ wphi, u16* __restrict__ wplo, float* __restrict__ bpo,
    u16* __restrict__ wWo, float* __restrict__ bWo)
{
  __shared__ float red[4];
  const int blk = blockIdx.x, tid = threadIdx.x;
  if (blk < 384) {
    const int p = blk >> 7, o = blk & 127;
    const float *ga, *be, *me, *va, *wm, *bi;
    if (p == 0)      { ga = gg; be = gbe; me = gme; va = gva; wm = gw; bi = gbi; }
    else if (p == 1) { ga = tg; be = tbe; me = tme; va = tva; wm = tw; bi = tbi; }
    else             { ga = pg; be = pbe; me = pme; va = pva; wm = pw; bi = pbi; }
    float s = ga[tid] * rsqrtf(va[tid] + 1e-5f);
    float t = be[tid] - me[tid] * s;
    float wv = wm[o * 256 + tid];
    float val = wv * s;
    if (p == 0) {
      wgo[o * 256 + tid] = f2bf(val);
    } else {
      u16 hi = f2bf(val);
      u16 lo = f2bf(val - bf2f(hi));
      if (p == 1) { wthi[o * 256 + tid] = hi; wtlo[o * 256 + tid] = lo; }
      else        { wphi[o * 256 + tid] = hi; wplo[o * 256 + tid] = lo; }
    }
    float part = t * wv;
#pragma unroll
    for (int off = 32; off; off >>= 1) part += __shfl_down(part, off);
    if ((tid & 63) == 0) red[tid >> 6] = part;
    __syncthreads();
    if (tid == 0) {
      float bsum = bi[o] + red[0] + red[1] + red[2] + red[3];
      if (p == 0) bgo[o] = bsum; else if (p == 1) bto[o] = bsum; else bpo[o] = bsum;
    }
  } else {
    const int c = blk - 384;
    float sW = Wg2[c] * rsqrtf(Wva[c] + 1e-5f);
    if (tid < 128) wWo[c * 128 + tid] = f2bf(Ww[c * 128 + tid] * sW);
    if (tid == 0) bWo[c] = Wb[c] * sW + Wbe[c] - Wme[c] * sW;
  }
}

// ---------------- K1: transpose-free — qb [c][v] packed hi|lo; fragments built in registers ----------------
// d_out slice (u16, stride 46080): [0,12288) g ; [12288,36864) thT_pk u32[96][128] ; [36864,46080) As (by k2)
__global__ __launch_bounds__(512, 6) void k1_conv(
    const float* __restrict__ x1, const float* __restrict__ x2,
    const u16* __restrict__ wG, const float* __restrict__ bG,
    const u16* __restrict__ wTh, const u16* __restrict__ wTl, const float* __restrict__ bT,
    const u16* __restrict__ wPh, const u16* __restrict__ wPl, const float* __restrict__ bP,
    u32* __restrict__ thRm, u32* __restrict__ phRm,
    u16* __restrict__ outU,
    float* __restrict__ m1t, float* __restrict__ x2cm, float* __restrict__ x1am)
{
  __shared__ u32 qb[128 * 97];     // 49,664 B: [c 0..127][v 0..96], hi|lo packed; v 90..95 zero
  __shared__ float red[8];
  const int b = blockIdx.x, tid = threadIdx.x;
  const int l = tid & 63, wv = tid >> 6, lr = l & 15, lq = l >> 4;
  const f32x4 zero = {0.f, 0.f, 0.f, 0.f};

  // zero v-pads once (never overwritten: loads touch only v<90)
  for (int t = tid; t < 128 * 6; t += 512) {
    int c = t / 6, v = 90 + t % 6;
    qb[c * 97 + v] = 0u;
  }

  auto doPhase = [&](const float* __restrict__ xb,
                     const u16* __restrict__ Wh, const u16* __restrict__ Wl, const float* __restrict__ biasT,
                     u32* __restrict__ rmDst, u32* __restrict__ pkDst, u16* __restrict__ gDst, bool isX1) {
    f32x4 aT[6], aG[6];
#pragma unroll
    for (int i = 0; i < 6; ++i) { aT[i] = zero; aG[i] = zero; }
    float cs = 0.f;
    for (int h = 0; h < 2; ++h) {
      __syncthreads();   // qb safe to overwrite (previous interval's reads done)
      // coalesced load + truncation split, native [c][v] orientation
      const float* src = xb + h * 11520;
      for (int t = tid; t < 5760; t += 512) {
        float2 f = *(const float2*)(src + 2 * t);
        int e = 2 * t, c = e / 90, v = e - 90 * c;
        qb[c * 97 + v]     = tsplit(f.x);
        qb[c * 97 + v + 1] = tsplit(f.y);
      }
      __syncthreads();
      // means (conflict-free qb reads)
      if (isX1) {
        if (tid < 128) {
          float s = 0.f;
          for (int v = 0; v < 90; ++v) {
            u32 p = qb[tid * 97 + v];
            s += bf2f((u16)p) + bf2f((u16)(p >> 16));
          }
          m1t[b * 256 + 128 * h + tid] = s * (1.f / 90.f);
#pragma unroll
          for (int o = 32; o; o >>= 1) s += __shfl_down(s, o);
          if ((tid & 63) == 0) red[(tid >> 6) + 2 * h] = s;
        }
      } else {
        if (tid < 90) {
          float s = 0.f;
          for (int c = 0; c < 128; ++c) {
            u32 p = qb[c * 97 + tid];
            s += bf2f((u16)p) + bf2f((u16)(p >> 16));
          }
          cs += s;
        }
      }
      // MFMA: fragments built in registers from qb
      for (int kk = 0; kk < 4; ++kk) {
        const int wo = (16 * wv + lr) * 256 + 128 * h + kk * 32 + 8 * lq;
        bf16x8 ah = *(const bf16x8*)(Wh + wo);
        bf16x8 al = *(const bf16x8*)(Wl + wo);
        bf16x8 ag = *(const bf16x8*)(wG + wo);
        const int c0 = kk * 32 + 8 * lq;
#pragma unroll
        for (int nt = 0; nt < 6; ++nt) {
          const int v = 16 * nt + lr;
          const u32* qp = qb + c0 * 97 + v;
          u32 w0 = qp[0], w1 = qp[97], w2 = qp[194], w3 = qp[291];
          u32 w4 = qp[388], w5 = qp[485], w6 = qp[582], w7 = qp[679];
          uint4 hh, ll;
          hh.x = (w0 & 0xFFFFu) | (w1 << 16);
          hh.y = (w2 & 0xFFFFu) | (w3 << 16);
          hh.z = (w4 & 0xFFFFu) | (w5 << 16);
          hh.w = (w6 & 0xFFFFu) | (w7 << 16);
          ll.x = (w0 >> 16) | (w1 & 0xFFFF0000u);
          ll.y = (w2 >> 16) | (w3 & 0xFFFF0000u);
          ll.z = (w4 >> 16) | (w5 & 0xFFFF0000u);
          ll.w = (w6 >> 16) | (w7 & 0xFFFF0000u);
          bf16x8 bh = __builtin_bit_cast(bf16x8, hh);
          bf16x8 bl = __builtin_bit_cast(bf16x8, ll);
          aT[nt] = MFMA16(ah, bh, aT[nt]);
          aT[nt] = MFMA16(ah, bl, aT[nt]);
          aT[nt] = MFMA16(al, bh, aT[nt]);
          aG[nt] = MFMA16(ag, bh, aG[nt]);
        }
      }
    }
    __syncthreads();   // red visibility; all qb reads complete
    // epilogue (identical to r11)
    const int c0 = 16 * wv + 4 * lq;
    const float4 bt4 = *(const float4*)(biasT + c0);
    const float4 bg4 = *(const float4*)(bG + c0);
#pragma unroll
    for (int nt = 0; nt < 6; ++nt) {
      const int v = 16 * nt + lr;
      u32 pk0, pk1, pk2, pk3; uint2 gpk;
      if (v < 90) {
        pk0 = tsplit(aT[nt][0] + bt4.x);
        pk1 = tsplit(aT[nt][1] + bt4.y);
        pk2 = tsplit(aT[nt][2] + bt4.z);
        pk3 = tsplit(aT[nt][3] + bt4.w);
        gpk.x = packbf2(aG[nt][0] + bg4.x, aG[nt][1] + bg4.y);
        gpk.y = packbf2(aG[nt][2] + bg4.z, aG[nt][3] + bg4.w);
      } else { pk0 = pk1 = pk2 = pk3 = 0u; gpk.x = 0u; gpk.y = 0u; }
      uint4 q4; q4.x = pk0; q4.y = pk1; q4.z = pk2; q4.w = pk3;
      *(uint4*)(pkDst + v * 128 + c0) = q4;            // thT_pk [v][ci]
      rmDst[(c0 + 0) * 96 + v] = pk0;                  // th_rm [ci][v]
      rmDst[(c0 + 1) * 96 + v] = pk1;
      rmDst[(c0 + 2) * 96 + v] = pk2;
      rmDst[(c0 + 3) * 96 + v] = pk3;
      *(uint2*)(gDst + v * 128 + c0) = gpk;            // g bf16 [v][ci]
    }
    if (isX1) {
      if (tid == 0) x1am[b] = (red[0] + red[1] + red[2] + red[3]) * (1.f / 23040.f);
    } else {
      if (tid < 90) x2cm[b * 96 + tid] = cs * (1.f / 256.f);
    }
  };

  u16* o1 = outU + (size_t)b * 46080;
  u16* o2 = outU + (size_t)(1024 + b) * 46080;
  doPhase(x1 + (size_t)b * 23040, wTh, wTl, bT,
          thRm + (size_t)b * 12288, (u32*)(o1 + 12288), o1, true);
  doPhase(x2 + (size_t)b * 23040, wPh, wPl, bP,
          phRm + (size_t)b * 12288, (u32*)(o2 + 12288), o2, false);
}

// ---------------- K2: both score matrices per block (r11-exact) ----------------
__global__ __launch_bounds__(512) void k2_attn(
    const u32* __restrict__ thRm, const u32* __restrict__ phRm,
    u16* __restrict__ outU,
    u16* __restrict__ At1g, u16* __restrict__ At2g)
{
  __shared__ __align__(16) char smem[108544];
  u16* s0 = (u16*)smem;
  float* st = (float*)(smem + 106496);
  float* eL = (float*)smem;

  const int b = blockIdx.x, tid = threadIdx.x;
  const int l = tid & 63, wv = tid >> 6, lr = l & 15, lq = l >> 4;
  const f32x4 zero = {0.f, 0.f, 0.f, 0.f};

  const u32* thRmB = thRm + (size_t)b * 12288;
  const u32* phRmB = phRm + (size_t)b * 12288;
  const u32* thPk = (const u32*)(outU + (size_t)b * 46080 + 12288);
  const u32* phPk = (const u32*)(outU + (size_t)(1024 + b) * 46080 + 12288);
  u32* S1 = (u32*)(outU + (size_t)(1024 + b) * 46080 + 36864);
  u32* S2 = (u32*)(outU + (size_t)b * 46080 + 36864);

  // ===== phase 1: e_time (row-major [ci][v], K=96) =====
  u16* th_hi = s0;
  u16* th_lo = s0 + 13312;
  u16* ph_hi = s0 + 26624;
  u16* ph_lo = s0 + 39936;
  for (int d = tid; d < 6144; d += 512) {
    int ten = (d >= 3072);
    int i = d - 3072 * ten;
    int ci = i / 24, q4 = i - 24 * ci;
    uint4 P = *(const uint4*)((ten ? phRmB : thRmB) + ci * 96 + 4 * q4);
    uint2 hi, lo;
    hi.x = (P.x & 0xFFFFu) | (P.y << 16);
    hi.y = (P.z & 0xFFFFu) | (P.w << 16);
    lo.x = (P.x >> 16) | (P.y & 0xFFFF0000u);
    lo.y = (P.z >> 16) | (P.w & 0xFFFF0000u);
    *(uint2*)((ten ? ph_hi : th_hi) + ci * 104 + 4 * q4) = hi;
    *(uint2*)((ten ? ph_lo : th_lo) + ci * 104 + 4 * q4) = lo;
  }
  __syncthreads();
  f32x4 acc[8];
#pragma unroll
  for (int nt = 0; nt < 8; ++nt) acc[nt] = zero;
#pragma unroll
  for (int kk = 0; kk < 3; ++kk) {
    const int ao = (16 * wv + lr) * 104 + kk * 32 + 8 * lq;
    bf16x8 ah = *(const bf16x8*)&th_hi[ao];
    bf16x8 al = *(const bf16x8*)&th_lo[ao];
#pragma unroll
    for (int nt = 0; nt < 8; ++nt) {
      const int bo = (16 * nt + lr) * 104 + kk * 32 + 8 * lq;
      bf16x8 bh = *(const bf16x8*)&ph_hi[bo];
      bf16x8 bl = *(const bf16x8*)&ph_lo[bo];
      acc[nt] = MFMA16(ah, bh, acc[nt]);
      acc[nt] = MFMA16(ah, bl, acc[nt]);
      acc[nt] = MFMA16(al, bh, acc[nt]);
    }
  }
  __syncthreads();   // staging reads done -> overlay eL
#pragma unroll
  for (int nt = 0; nt < 8; ++nt)
#pragma unroll
    for (int r = 0; r < 4; ++r)
      eL[(16 * nt + lr) * 133 + 16 * wv + 4 * lq + r] = acc[nt][r];
  __syncthreads();
  if (tid < 128) {
    int j = tid; float m = -1e30f;
    for (int i = 0; i < 128; ++i) m = fmaxf(m, eL[j * 133 + i]);
    float s = 0.f;
    for (int i = 0; i < 128; ++i) s += __expf(eL[j * 133 + i] - m);
    st[j] = m; st[128 + j] = 1.f / s;
  } else if (tid < 256) {
    int i = tid - 128; float m = -1e30f;
    for (int j = 0; j < 128; ++j) m = fmaxf(m, eL[j * 133 + i]);
    float s = 0.f;
    for (int j = 0; j < 128; ++j) s += __expf(eL[j * 133 + i] - m);
    st[256 + i] = m; st[384 + i] = 1.f / s;
  }
  __syncthreads();
  {
    u32* A1 = (u32*)(At1g + (size_t)b * 16384);
    u32* A2 = (u32*)(At2g + (size_t)b * 16384);
    for (int d = tid; d < 8192; d += 512) {
      int i = d >> 6, jp = d & 63;
      float m1 = st[256 + i], s1v = st[384 + i];
      float a0 = __expf(eL[(2 * jp) * 133 + i] - m1) * s1v;
      float a1 = __expf(eL[(2 * jp + 1) * 133 + i] - m1) * s1v;
      A1[d] = packbf2(a0, a1);
      float m2 = st[i], s2v = st[128 + i];
      float b0 = __expf(eL[i * 133 + 2 * jp] - m2) * s2v;
      float b1 = __expf(eL[i * 133 + 2 * jp + 1] - m2) * s2v;
      A2[d] = packbf2(b0, b1);
    }
  }
  __syncthreads();

  // ===== phase 2: e_space (transposed [v][ci], K=128) =====
  u16* tTh = s0;
  u16* tTl = s0 + 13056;
  u16* pTh = s0 + 26112;
  u16* pTl = s0 + 39168;
  for (int d = tid; d < 6144; d += 512) {
    int ten = (d >= 3072);
    int i = d - 3072 * ten;
    int v = i >> 5, q4 = i & 31;
    uint4 P = *(const uint4*)((ten ? phPk : thPk) + v * 128 + 4 * q4);
    uint2 hi, lo;
    hi.x = (P.x & 0xFFFFu) | (P.y << 16);
    hi.y = (P.z & 0xFFFFu) | (P.w << 16);
    lo.x = (P.x >> 16) | (P.y & 0xFFFF0000u);
    lo.y = (P.z >> 16) | (P.w & 0xFFFF0000u);
    *(uint2*)((ten ? pTh : tTh) + v * 136 + 4 * q4) = hi;
    *(uint2*)((ten ? pTl : tTl) + v * 136 + 4 * q4) = lo;
  }
  __syncthreads();
  f32x4 accS[5];
#pragma unroll
  for (int it = 0; it < 5; ++it) accS[it] = zero;
#pragma unroll
  for (int it = 0; it < 5; ++it) {
    const int t5 = wv + 8 * it;
    if (t5 < 36) {
      const int mt = t5 / 6, nt = t5 - 6 * (t5 / 6);
#pragma unroll
      for (int kk = 0; kk < 4; ++kk) {
        const int ao = (16 * mt + lr) * 136 + kk * 32 + 8 * lq;
        const int bo = (16 * nt + lr) * 136 + kk * 32 + 8 * lq;
        bf16x8 ah = *(const bf16x8*)&tTh[ao];
        bf16x8 al = *(const bf16x8*)&tTl[ao];
        bf16x8 bh = *(const bf16x8*)&pTh[bo];
        bf16x8 bl = *(const bf16x8*)&pTl[bo];
        accS[it] = MFMA16(ah, bh, accS[it]);
        accS[it] = MFMA16(ah, bl, accS[it]);
        accS[it] = MFMA16(al, bh, accS[it]);
      }
    }
  }
  __syncthreads();
  {
    float* esL = (float*)smem;
#pragma unroll
    for (int it = 0; it < 5; ++it) {
      const int t5 = wv + 8 * it;
      if (t5 < 36) {
        const int mt = t5 / 6, nt = t5 - 6 * (t5 / 6);
#pragma unroll
        for (int r = 0; r < 4; ++r)
          esL[(16 * nt + lr) * 101 + 16 * mt + 4 * lq + r] = accS[it][r];
      }
    }
  }
  __syncthreads();
  {
    float* esL = (float*)smem;
    if (tid < 96) {
      int v = tid; float m = -1e30f;
      for (int w2 = 0; w2 < 90; ++w2) m = fmaxf(m, esL[v * 101 + w2]);
      float s = 0.f;
      for (int w2 = 0; w2 < 90; ++w2) s += __expf(esL[v * 101 + w2] - m);
      st[v] = m; st[128 + v] = 1.f / s;
    } else if (tid >= 128 && tid < 224) {
      int v = tid - 128; float m = -1e30f;
      for (int w2 = 0; w2 < 90; ++w2) m = fmaxf(m, esL[w2 * 101 + v]);
      float s = 0.f;
      for (int w2 = 0; w2 < 90; ++w2) s += __expf(esL[w2 * 101 + v] - m);
      st[256 + v] = m; st[384 + v] = 1.f / s;
    }
  }
  __syncthreads();
  {
    float* esL = (float*)smem;
    for (int d = tid; d < 4608; d += 512) {
      int w2 = d / 48, vp = d - 48 * (d / 48);
      int v0 = 2 * vp, v1 = v0 + 1;
      float a0 = __expf(esL[v0 * 101 + w2] - st[v0]) * st[128 + v0];
      float a1 = __expf(esL[v1 * 101 + w2] - st[v1]) * st[128 + v1];
      S1[d] = packbf2(a0, a1);
      float b0 = __expf(esL[w2 * 101 + v0] - st[256 + v0]) * st[384 + v0];
      float b1 = __expf(esL[w2 * 101 + v1] - st[256 + v1]) * st[384 + v1];
      S2[d] = packbf2(b0, b1);
    }
  }
}

// ---------------- K3: r11 structure (unchanged) ----------------
// smem: areaA [0,26624) = gT [96][136] then ZT [96][136]; areaB [26624,53248) = Tb [128][104]
__global__ __launch_bounds__(256) void k3_out(
    const float* __restrict__ x1, const float* __restrict__ x2,
    const u16* __restrict__ At1g, const u16* __restrict__ At2g,
    const u16* __restrict__ wW, const float* __restrict__ bW,
    const float* __restrict__ m1t, const float* __restrict__ x2cm, const float* __restrict__ x1am,
    float* __restrict__ out)
{
  __shared__ __align__(16) char smem[53248];
  u16* gT = (u16*)smem;                    // [96][136]
  u16* ZT = (u16*)smem;                    // overlays gT after T-pass
  u16* Tb = (u16*)(smem + 26624);          // [128][104]
  const int b = blockIdx.x, tid = threadIdx.x;
  const int l = tid & 63, wv = tid >> 6, lr = l & 15, lq = l >> 4;
  const f32x4 zero = {0.f, 0.f, 0.f, 0.f};

  float* out1 = out + (size_t)b * 23040;
  float* out2 = out + (size_t)23040 * 1024 + (size_t)b * 23040;
  const u16* g1s = (const u16*)out1;
  const u16* g2s = (const u16*)out2;
  const u16* As1 = (const u16*)out2 + 36864;
  const u16* As2 = (const u16*)out1 + 36864;

  auto phase = [&](const u16* __restrict__ gsrc, const u16* __restrict__ At,
                   const u16* __restrict__ AsT, const float* __restrict__ xres,
                   float* __restrict__ dst, bool modeA) {
    // 1. stage g [96][136]
    for (int i = tid; i < 1536; i += 256) {
      int v = i >> 4, hh = i & 15;
      *(uint4*)&gT[v * 136 + 8 * hh] = ((const uint4*)gsrc)[i];
    }
    __syncthreads();
    // 2. T-pass: T[i][v] = sum_j At[i][j]*g[j][v] -> Tb row-major [128][104]
#pragma unroll
    for (int ni = 0; ni < 2; ++ni) {
      const int nt = 2 * wv + ni;
      f32x4 acc[6];
#pragma unroll
      for (int i = 0; i < 6; ++i) acc[i] = zero;
#pragma unroll
      for (int kk = 0; kk < 4; ++kk) {
        bf16x8 bb = *(const bf16x8*)(At + (16 * nt + lr) * 128 + kk * 32 + 8 * lq);
#pragma unroll
        for (int mt = 0; mt < 6; ++mt) {
          bf16x8 a = *(const bf16x8*)&gT[(16 * mt + lr) * 136 + kk * 32 + 8 * lq];
          acc[mt] = MFMA16(a, bb, acc[mt]);
        }
      }
#pragma unroll
      for (int mt = 0; mt < 6; ++mt) {
        uint2 pk;
        pk.x = packbf2(acc[mt][0], acc[mt][1]);
        pk.y = packbf2(acc[mt][2], acc[mt][3]);
        *(uint2*)&Tb[(16 * nt + lr) * 104 + 16 * mt + 4 * lq] = pk;
      }
    }
    __syncthreads();   // all gT reads complete -> areaA reusable as ZT
    // 3. Z-pass: Z[i][w] = sum_v T[i][v]*AsT[w][v] -> ZT = Z^T [96][136] (overlay gT)
    {
      f32x4 acc[2][6];
#pragma unroll
      for (int i = 0; i < 2; ++i)
#pragma unroll
        for (int j = 0; j < 6; ++j) acc[i][j] = zero;
#pragma unroll
      for (int kk = 0; kk < 3; ++kk) {
        bf16x8 a0 = *(const bf16x8*)&Tb[(16 * (2 * wv) + lr) * 104 + kk * 32 + 8 * lq];
        bf16x8 a1 = *(const bf16x8*)&Tb[(16 * (2 * wv + 1) + lr) * 104 + kk * 32 + 8 * lq];
#pragma unroll
        for (int nt = 0; nt < 6; ++nt) {
          bf16x8 bb = *(const bf16x8*)(AsT + (16 * nt + lr) * 96 + kk * 32 + 8 * lq);
          acc[0][nt] = MFMA16(a0, bb, acc[0][nt]);
          acc[1][nt] = MFMA16(a1, bb, acc[1][nt]);
        }
      }
#pragma unroll
      for (int mi = 0; mi < 2; ++mi) {
        const int mt = 2 * wv + mi;
#pragma unroll
        for (int nt = 0; nt < 6; ++nt) {
          uint2 pk;
          pk.x = packbf2(acc[mi][nt][0], acc[mi][nt][1]);
          pk.y = packbf2(acc[mi][nt][2], acc[mi][nt][3]);
          *(uint2*)&ZT[(16 * nt + lr) * 136 + 16 * mt + 4 * lq] = pk;
        }
      }
    }
    __syncthreads();
    // 4. O-pass: O = Wf @ Z + epilogue
    const float am = modeA ? 0.f : x1am[b];
#pragma unroll
    for (int mi = 0; mi < 4; ++mi) {
      const int mt = 4 * wv + mi;
      f32x4 acc[6];
#pragma unroll
      for (int i = 0; i < 6; ++i) acc[i] = zero;
#pragma unroll
      for (int kk = 0; kk < 4; ++kk) {
        bf16x8 a = *(const bf16x8*)(wW + (16 * mt + lr) * 128 + kk * 32 + 8 * lq);
#pragma unroll
        for (int nt = 0; nt < 6; ++nt) {
          bf16x8 bb = *(const bf16x8*)&ZT[(16 * nt + lr) * 136 + kk * 32 + 8 * lq];
          acc[nt] = MFMA16(a, bb, acc[nt]);
        }
      }
      const int c0 = 16 * mt + 4 * lq;
      const float4 bw4 = *(const float4*)(bW + c0);
      float bwA[4] = {bw4.x, bw4.y, bw4.z, bw4.w};
      float mA[4] = {0.f, 0.f, 0.f, 0.f};
      if (modeA) {
        const float4 m4 = *(const float4*)(m1t + b * 256 + c0);
        mA[0] = m4.x; mA[1] = m4.y; mA[2] = m4.z; mA[3] = m4.w;
      }
#pragma unroll
      for (int nt = 0; nt < 6; ++nt) {
        const int v = 16 * nt + lr;
        if (v < 90) {
          const float addv = modeA ? 0.f : (am + x2cm[b * 96 + v]);
#pragma unroll
          for (int r = 0; r < 4; ++r) {
            const int c = c0 + r;
            const float extra = modeA ? mA[r] : addv;
            dst[c * 90 + v] = xres[c * 90 + v] + acc[nt][r] + bwA[r] + extra;
          }
        }
      }
    }
    __syncthreads();   // all ZT reads done before next phase restages gT into areaA
  };

  phase(g2s, At1g + (size_t)b * 16384, As1, x2 + (size_t)b * 23040, out2, true);
  phase(g1s, At2g + (size_t)b * 16384, As2, x1 + (size_t)b * 23040, out1, false);
}

} // namespace

extern "C" void kernel_launch(void* const* d_in, const int* in_sizes, int n_in,
                              void* d_out, int out_size, void* d_ws, size_t ws_size,
                              hipStream_t stream)
{
  (void)in_sizes; (void)n_in; (void)out_size; (void)ws_size;
  const float* x1  = (const float*)d_in[0];
  const float* x2  = (const float*)d_in[1];
  const float* gg  = (const float*)d_in[2];
  const float* gbe = (const float*)d_in[3];
  const float* gme = (const float*)d_in[4];
  const float* gva = (const float*)d_in[5];
  const float* gw  = (const float*)d_in[6];
  const float* gbi = (const float*)d_in[7];
  const float* tg  = (const float*)d_in[8];
  const float* tbe = (const float*)d_in[9];
  const float* tme = (const float*)d_in[10];
  const float* tva = (const float*)d_in[11];
  const float* tw  = (const float*)d_in[12];
  const float* tbi = (const float*)d_in[13];
  const float* pg  = (const float*)d_in[14];
  const float* pbe = (const float*)d_in[15];
  const float* pme = (const float*)d_in[16];
  const float* pva = (const float*)d_in[17];
  const float* pw  = (const float*)d_in[18];
  const float* pbi = (const float*)d_in[19];
  const float* Ww  = (const float*)d_in[20];
  const float* Wb  = (const float*)d_in[21];
  const float* Wg  = (const float*)d_in[22];
  const float* Wbe = (const float*)d_in[23];
  const float* Wme = (const float*)d_in[24];
  const float* Wva = (const float*)d_in[25];
  // d_in[26..33] (qt/ks/qs/kt) are dead: softmax over singleton axis == 1.

  float* out = (float*)d_out;
  unsigned char* W8 = (unsigned char*)d_ws;

  size_t off = 0;
  auto al = [&](size_t n) { size_t r = off; off += (n + 255) & ~(size_t)255; return r; };
  const size_t oWG  = al(65536);
  const size_t oWTh = al(65536), oWTl = al(65536);
  const size_t oWPh = al(65536), oWPl = al(65536);
  const size_t oWW  = al(65536);
  const size_t oBG = al(512), oBT = al(512), oBP = al(512), oBW = al(1024);
  const size_t oRM1 = al((size_t)B * 49152), oRM2 = al((size_t)B * 49152);
  const size_t oA1 = al((size_t)B * 32768), oA2 = al((size_t)B * 32768);
  const size_t oM1 = al((size_t)B * 1024), oXC = al((size_t)B * 384), oXA = al((size_t)B * 4);
  // total ~168.4 MB; thT_pk/phT_pk/As1/As2 live in unused d_out space.

  k0_fold<<<dim3(640), dim3(256), 0, stream>>>(
      gg, gbe, gme, gva, gw, gbi,
      tg, tbe, tme, tva, tw, tbi,
      pg, pbe, pme, pva, pw, pbi,
      Ww, Wb, Wg, Wbe, Wme, Wva,
      (u16*)(W8 + oWG), (float*)(W8 + oBG),
      (u16*)(W8 + oWTh), (u16*)(W8 + oWTl), (float*)(W8 + oBT),
      (u16*)(W8 + oWPh), (u16*)(W8 + oWPl), (float*)(W8 + oBP),
      (u16*)(W8 + oWW), (float*)(W8 + oBW));

  k1_conv<<<dim3(B), dim3(512), 0, stream>>>(
      x1, x2,
      (const u16*)(W8 + oWG), (const float*)(W8 + oBG),
      (const u16*)(W8 + oWTh), (const u16*)(W8 + oWTl), (const float*)(W8 + oBT),
      (const u16*)(W8 + oWPh), (const u16*)(W8 + oWPl), (const float*)(W8 + oBP),
      (u32*)(W8 + oRM1), (u32*)(W8 + oRM2),
      (u16*)out,
      (float*)(W8 + oM1), (float*)(W8 + oXC), (float*)(W8 + oXA));

  k2_attn<<<dim3(B), dim3(512), 0, stream>>>(
      (const u32*)(W8 + oRM1), (const u32*)(W8 + oRM2),
      (u16*)out,
      (u16*)(W8 + oA1), (u16*)(W8 + oA2));

  k3_out<<<dim3(B), dim3(256), 0, stream>>>(
      x1, x2,
      (const u16*)(W8 + oA1), (const u16*)(W8 + oA2),
      (const u16*)(W8 + oWW), (const float*)(W8 + oBW),
      (const float*)(W8 + oM1), (const float*)(W8 + oXC), (const float*)(W8 + oXA),
      out);
}

// Round 13
// 451.189 us; speedup vs baseline: 1.8136x; 1.8136x over previous
//
#include <hip/hip_runtime.h>

namespace {

constexpr int B = 1024;

using u16 = unsigned short;
using u32 = unsigned int;

typedef __attribute__((ext_vector_type(8))) short bf16x8;
typedef __attribute__((ext_vector_type(4))) float f32x4;

#define MFMA16(a, b, c) __builtin_amdgcn_mfma_f32_16x16x32_bf16(a, b, c, 0, 0, 0)

__device__ __forceinline__ u16 f2bf(float f) {
  u32 u = __builtin_bit_cast(u32, f);
  u += 0x7FFFu + ((u >> 16) & 1u);          // RNE
  return (u16)(u >> 16);
}
__device__ __forceinline__ float bf2f(u16 s) {
  u32 u = ((u32)s) << 16;
  return __builtin_bit_cast(float, u);
}
__device__ __forceinline__ u32 packbf2(float a, float b) {
  return (u32)f2bf(a) | ((u32)f2bf(b) << 16);
}
// truncation split (kept for k2 staging paths that expect packed hi|lo)
__device__ __forceinline__ u32 tsplit(float f) {
  u32 u = __builtin_bit_cast(u32, f);
  float r = f - __builtin_bit_cast(float, u & 0xFFFF0000u);
  u32 ur = __builtin_bit_cast(u32, r);
  return (u >> 16) | (ur & 0xFFFF0000u);
}

// ---------------- K0: fold BN into conv weights ----------------
__global__ __launch_bounds__(256) void k0_fold(
    const float* __restrict__ gg, const float* __restrict__ gbe, const float* __restrict__ gme, const float* __restrict__ gva,
    const float* __restrict__ gw, const float* __restrict__ gbi,
    const float* __restrict__ tg, const float* __restrict__ tbe, const float* __restrict__ tme, const float* __restrict__ tva,
    const float* __restrict__ tw, const float* __restrict__ tbi,
    const float* __restrict__ pg, const float* __restrict__ pbe, const float* __restrict__ pme, const float* __restrict__ pva,
    const float* __restrict__ pw, const float* __restrict__ pbi,
    const float* __restrict__ Ww, const float* __restrict__ Wb,
    const float* __restrict__ Wg2, const float* __restrict__ Wbe, const float* __restrict__ Wme, const float* __restrict__ Wva,
    u16* __restrict__ wgo, float* __restrict__ bgo,
    u16* __restrict__ wthi, u16* __restrict__ wtlo, float* __restrict__ bto,
    u16* __restrict__ wphi, u16* __restrict__ wplo, float* __restrict__ bpo,
    u16* __restrict__ wWo, float* __restrict__ bWo)
{
  __shared__ float red[4];
  const int blk = blockIdx.x, tid = threadIdx.x;
  if (blk < 384) {
    const int p = blk >> 7, o = blk & 127;
    const float *ga, *be, *me, *va, *wm, *bi;
    if (p == 0)      { ga = gg; be = gbe; me = gme; va = gva; wm = gw; bi = gbi; }
    else if (p == 1) { ga = tg; be = tbe; me = tme; va = tva; wm = tw; bi = tbi; }
    else             { ga = pg; be = pbe; me = pme; va = pva; wm = pw; bi = pbi; }
    float s = ga[tid] * rsqrtf(va[tid] + 1e-5f);
    float t = be[tid] - me[tid] * s;
    float wv = wm[o * 256 + tid];
    float val = wv * s;
    if (p == 0) {
      wgo[o * 256 + tid] = f2bf(val);
    } else {
      u16 hi = f2bf(val);
      u16 lo = f2bf(val - bf2f(hi));
      if (p == 1) { wthi[o * 256 + tid] = hi; wtlo[o * 256 + tid] = lo; }
      else        { wphi[o * 256 + tid] = hi; wplo[o * 256 + tid] = lo; }
    }
    float part = t * wv;
#pragma unroll
    for (int off = 32; off; off >>= 1) part += __shfl_down(part, off);
    if ((tid & 63) == 0) red[tid >> 6] = part;
    __syncthreads();
    if (tid == 0) {
      float bsum = bi[o] + red[0] + red[1] + red[2] + red[3];
      if (p == 0) bgo[o] = bsum; else if (p == 1) bto[o] = bsum; else bpo[o] = bsum;
    }
  } else {
    const int c = blk - 384;
    float sW = Wg2[c] * rsqrtf(Wva[c] + 1e-5f);
    if (tid < 128) wWo[c * 128 + tid] = f2bf(Ww[c * 128 + tid] * sW);
    if (tid == 0) bWo[c] = Wb[c] * sW + Wbe[c] - Wme[c] * sW;
  }
}

// ---------------- K1: round-5 exact (measured 193 us): RNE hi/lo split, 4-quarter qb transpose ----------------
// d_out slice (u16, stride 46080): [0,12288) g ; [12288,36864) thT_pk u32[96][128] ; [36864,46080) As (by k2)
__global__ __launch_bounds__(512, 4) void k1_conv(
    const float* __restrict__ x1, const float* __restrict__ x2,
    const u16* __restrict__ wG, const float* __restrict__ bG,
    const u16* __restrict__ wTh, const u16* __restrict__ wTl, const float* __restrict__ bT,
    const u16* __restrict__ wPh, const u16* __restrict__ wPl, const float* __restrict__ bP,
    u32* __restrict__ thRm, u32* __restrict__ phRm,
    u16* __restrict__ outU,
    float* __restrict__ m1t, float* __restrict__ x2cm, float* __restrict__ x1am)
{
  __shared__ u32 qb[64 * 92];       // 23552 B quarter: [ch][v] packed hi|lo
  __shared__ u16 xh[96 * 136];      // 26112 B
  __shared__ u16 xl[96 * 136];      // 26112 B  (total ~75.8 KB -> 2 blocks/CU)
  __shared__ float red[4];
  const int b = blockIdx.x, tid = threadIdx.x;
  const int l = tid & 63, wv = tid >> 6, lr = l & 15, lq = l >> 4;
  const f32x4 zero = {0.f, 0.f, 0.f, 0.f};

  auto doPhase = [&](const float* __restrict__ xb,
                     const u16* __restrict__ Wh, const u16* __restrict__ Wl, const float* __restrict__ biasT,
                     u32* __restrict__ rmDst, u32* __restrict__ pkDst, u16* __restrict__ gDst, bool isX1) {
    f32x4 aT[6], aG[6];
#pragma unroll
    for (int i = 0; i < 6; ++i) { aT[i] = zero; aG[i] = zero; }
    float cs = 0.f;
    for (int h = 0; h < 2; ++h) {
      for (int q = 0; q < 2; ++q) {
        __syncthreads();
        // pass 1: coalesced load + hi/lo split into qb [64ch][92v]
        const float* src = xb + (2 * h + q) * 5760;
        for (int t = tid; t < 2880; t += 512) {
          float2 f = *(const float2*)(src + 2 * t);
          int cl = (2 * t) / 90, v = 2 * t - 90 * cl;
          u16 h0 = f2bf(f.x); u16 l0 = f2bf(f.x - bf2f(h0));
          u16 h1 = f2bf(f.y); u16 l1 = f2bf(f.y - bf2f(h1));
          uint2 w; w.x = (u32)h0 | ((u32)l0 << 16); w.y = (u32)h1 | ((u32)l1 << 16);
          *(uint2*)&qb[cl * 92 + v] = w;
        }
        __syncthreads();
        // pass 2: transpose into xh/xl columns [64q, 64q+64)
        for (int t = tid; t < 1440; t += 512) {
          int v = t % 90, c4 = t / 90;
          u32 p0 = qb[(4 * c4 + 0) * 92 + v], p1 = qb[(4 * c4 + 1) * 92 + v];
          u32 p2 = qb[(4 * c4 + 2) * 92 + v], p3 = qb[(4 * c4 + 3) * 92 + v];
          uint2 hi, lo;
          hi.x = (p0 & 0xFFFFu) | (p1 << 16);
          hi.y = (p2 & 0xFFFFu) | (p3 << 16);
          lo.x = (p0 >> 16) | (p1 & 0xFFFF0000u);
          lo.y = (p2 >> 16) | (p3 & 0xFFFF0000u);
          int base = v * 136 + 64 * q + 4 * c4;
          *(uint2*)&xh[base] = hi;
          *(uint2*)&xl[base] = lo;
        }
        if (q == 1) {   // zero pad rows 90..95 (cols 0..127)
          for (int t = tid; t < 384; t += 512) {
            int v = 90 + (t >> 6), c2 = (t & 63) * 2;
            *(u32*)&xh[v * 136 + c2] = 0u;
            *(u32*)&xl[v * 136 + c2] = 0u;
          }
        }
      }
      __syncthreads();   // half fully staged
      // means (from hi+lo, error ~2^-17 rel)
      if (isX1) {
        if (tid < 128) {
          float s = 0.f;
          for (int v = 0; v < 90; ++v) s += bf2f(xh[v * 136 + tid]) + bf2f(xl[v * 136 + tid]);
          m1t[b * 256 + 128 * h + tid] = s * (1.f / 90.f);
#pragma unroll
          for (int o = 32; o; o >>= 1) s += __shfl_down(s, o);
          if ((tid & 63) == 0) red[(tid >> 6) + 2 * h] = s;
        }
      } else {
        if (tid < 90) {
          float s = 0.f;
          for (int cl = 0; cl < 128; ++cl) s += bf2f(xh[tid * 136 + cl]) + bf2f(xl[tid * 136 + cl]);
          cs += s;
        }
      }
      // MFMA over this half's 128 channels
      for (int kk = 0; kk < 4; ++kk) {
        const int wo = (16 * wv + lr) * 256 + 128 * h + kk * 32 + 8 * lq;
        bf16x8 ah = *(const bf16x8*)(Wh + wo);
        bf16x8 al = *(const bf16x8*)(Wl + wo);
        bf16x8 ag = *(const bf16x8*)(wG + wo);
#pragma unroll
        for (int nt = 0; nt < 6; ++nt) {
          const int bo = (16 * nt + lr) * 136 + kk * 32 + 8 * lq;
          bf16x8 bh = *(const bf16x8*)&xh[bo];
          bf16x8 bl = *(const bf16x8*)&xl[bo];
          aT[nt] = MFMA16(ah, bh, aT[nt]);
          aT[nt] = MFMA16(ah, bl, aT[nt]);
          aT[nt] = MFMA16(al, bh, aT[nt]);
          aG[nt] = MFMA16(ag, bh, aG[nt]);
        }
      }
    }
    __syncthreads();   // red visibility; all LDS reads complete
    // epilogue
    const int c0 = 16 * wv + 4 * lq;
    const float4 bt4 = *(const float4*)(biasT + c0);
    const float4 bg4 = *(const float4*)(bG + c0);
#pragma unroll
    for (int nt = 0; nt < 6; ++nt) {
      const int v = 16 * nt + lr;
      u32 pk0, pk1, pk2, pk3; uint2 gpk;
      if (v < 90) {
        float t0 = aT[nt][0] + bt4.x, t1 = aT[nt][1] + bt4.y;
        float t2 = aT[nt][2] + bt4.z, t3 = aT[nt][3] + bt4.w;
        u16 h0 = f2bf(t0), h1 = f2bf(t1), h2 = f2bf(t2), h3 = f2bf(t3);
        pk0 = (u32)h0 | ((u32)f2bf(t0 - bf2f(h0)) << 16);
        pk1 = (u32)h1 | ((u32)f2bf(t1 - bf2f(h1)) << 16);
        pk2 = (u32)h2 | ((u32)f2bf(t2 - bf2f(h2)) << 16);
        pk3 = (u32)h3 | ((u32)f2bf(t3 - bf2f(h3)) << 16);
        gpk.x = packbf2(aG[nt][0] + bg4.x, aG[nt][1] + bg4.y);
        gpk.y = packbf2(aG[nt][2] + bg4.z, aG[nt][3] + bg4.w);
      } else { pk0 = pk1 = pk2 = pk3 = 0u; gpk.x = 0u; gpk.y = 0u; }
      uint4 q4; q4.x = pk0; q4.y = pk1; q4.z = pk2; q4.w = pk3;
      *(uint4*)(pkDst + v * 128 + c0) = q4;            // thT_pk [v][ci]
      rmDst[(c0 + 0) * 96 + v] = pk0;                  // th_rm [ci][v]
      rmDst[(c0 + 1) * 96 + v] = pk1;
      rmDst[(c0 + 2) * 96 + v] = pk2;
      rmDst[(c0 + 3) * 96 + v] = pk3;
      *(uint2*)(gDst + v * 128 + c0) = gpk;            // g bf16 [v][ci]
    }
    if (isX1) {
      if (tid == 0) x1am[b] = (red[0] + red[1] + red[2] + red[3]) * (1.f / 23040.f);
    } else {
      if (tid < 90) x2cm[b * 96 + tid] = cs * (1.f / 256.f);
    }
  };

  u16* o1 = outU + (size_t)b * 46080;
  u16* o2 = outU + (size_t)(1024 + b) * 46080;
  doPhase(x1 + (size_t)b * 23040, wTh, wTl, bT,
          thRm + (size_t)b * 12288, (u32*)(o1 + 12288), o1, true);
  doPhase(x2 + (size_t)b * 23040, wPh, wPl, bP,
          phRm + (size_t)b * 12288, (u32*)(o2 + 12288), o2, false);
}

// ---------------- K2: both score matrices per block (r11-exact, ~100 us) ----------------
__global__ __launch_bounds__(512) void k2_attn(
    const u32* __restrict__ thRm, const u32* __restrict__ phRm,
    u16* __restrict__ outU,
    u16* __restrict__ At1g, u16* __restrict__ At2g)
{
  __shared__ __align__(16) char smem[108544];
  u16* s0 = (u16*)smem;
  float* st = (float*)(smem + 106496);
  float* eL = (float*)smem;

  const int b = blockIdx.x, tid = threadIdx.x;
  const int l = tid & 63, wv = tid >> 6, lr = l & 15, lq = l >> 4;
  const f32x4 zero = {0.f, 0.f, 0.f, 0.f};

  const u32* thRmB = thRm + (size_t)b * 12288;
  const u32* phRmB = phRm + (size_t)b * 12288;
  const u32* thPk = (const u32*)(outU + (size_t)b * 46080 + 12288);
  const u32* phPk = (const u32*)(outU + (size_t)(1024 + b) * 46080 + 12288);
  u32* S1 = (u32*)(outU + (size_t)(1024 + b) * 46080 + 36864);
  u32* S2 = (u32*)(outU + (size_t)b * 46080 + 36864);

  // ===== phase 1: e_time (row-major [ci][v], K=96) =====
  u16* th_hi = s0;
  u16* th_lo = s0 + 13312;
  u16* ph_hi = s0 + 26624;
  u16* ph_lo = s0 + 39936;
  for (int d = tid; d < 6144; d += 512) {
    int ten = (d >= 3072);
    int i = d - 3072 * ten;
    int ci = i / 24, q4 = i - 24 * ci;
    uint4 P = *(const uint4*)((ten ? phRmB : thRmB) + ci * 96 + 4 * q4);
    uint2 hi, lo;
    hi.x = (P.x & 0xFFFFu) | (P.y << 16);
    hi.y = (P.z & 0xFFFFu) | (P.w << 16);
    lo.x = (P.x >> 16) | (P.y & 0xFFFF0000u);
    lo.y = (P.z >> 16) | (P.w & 0xFFFF0000u);
    *(uint2*)((ten ? ph_hi : th_hi) + ci * 104 + 4 * q4) = hi;
    *(uint2*)((ten ? ph_lo : th_lo) + ci * 104 + 4 * q4) = lo;
  }
  __syncthreads();
  f32x4 acc[8];
#pragma unroll
  for (int nt = 0; nt < 8; ++nt) acc[nt] = zero;
#pragma unroll
  for (int kk = 0; kk < 3; ++kk) {
    const int ao = (16 * wv + lr) * 104 + kk * 32 + 8 * lq;
    bf16x8 ah = *(const bf16x8*)&th_hi[ao];
    bf16x8 al = *(const bf16x8*)&th_lo[ao];
#pragma unroll
    for (int nt = 0; nt < 8; ++nt) {
      const int bo = (16 * nt + lr) * 104 + kk * 32 + 8 * lq;
      bf16x8 bh = *(const bf16x8*)&ph_hi[bo];
      bf16x8 bl = *(const bf16x8*)&ph_lo[bo];
      acc[nt] = MFMA16(ah, bh, acc[nt]);
      acc[nt] = MFMA16(ah, bl, acc[nt]);
      acc[nt] = MFMA16(al, bh, acc[nt]);
    }
  }
  __syncthreads();   // staging reads done -> overlay eL
#pragma unroll
  for (int nt = 0; nt < 8; ++nt)
#pragma unroll
    for (int r = 0; r < 4; ++r)
      eL[(16 * nt + lr) * 133 + 16 * wv + 4 * lq + r] = acc[nt][r];
  __syncthreads();
  if (tid < 128) {
    int j = tid; float m = -1e30f;
    for (int i = 0; i < 128; ++i) m = fmaxf(m, eL[j * 133 + i]);
    float s = 0.f;
    for (int i = 0; i < 128; ++i) s += __expf(eL[j * 133 + i] - m);
    st[j] = m; st[128 + j] = 1.f / s;
  } else if (tid < 256) {
    int i = tid - 128; float m = -1e30f;
    for (int j = 0; j < 128; ++j) m = fmaxf(m, eL[j * 133 + i]);
    float s = 0.f;
    for (int j = 0; j < 128; ++j) s += __expf(eL[j * 133 + i] - m);
    st[256 + i] = m; st[384 + i] = 1.f / s;
  }
  __syncthreads();
  {
    u32* A1 = (u32*)(At1g + (size_t)b * 16384);
    u32* A2 = (u32*)(At2g + (size_t)b * 16384);
    for (int d = tid; d < 8192; d += 512) {
      int i = d >> 6, jp = d & 63;
      float m1 = st[256 + i], s1v = st[384 + i];
      float a0 = __expf(eL[(2 * jp) * 133 + i] - m1) * s1v;
      float a1 = __expf(eL[(2 * jp + 1) * 133 + i] - m1) * s1v;
      A1[d] = packbf2(a0, a1);
      float m2 = st[i], s2v = st[128 + i];
      float b0 = __expf(eL[i * 133 + 2 * jp] - m2) * s2v;
      float b1 = __expf(eL[i * 133 + 2 * jp + 1] - m2) * s2v;
      A2[d] = packbf2(b0, b1);
    }
  }
  __syncthreads();

  // ===== phase 2: e_space (transposed [v][ci], K=128) =====
  u16* tTh = s0;
  u16* tTl = s0 + 13056;
  u16* pTh = s0 + 26112;
  u16* pTl = s0 + 39168;
  for (int d = tid; d < 6144; d += 512) {
    int ten = (d >= 3072);
    int i = d - 3072 * ten;
    int v = i >> 5, q4 = i & 31;
    uint4 P = *(const uint4*)((ten ? phPk : thPk) + v * 128 + 4 * q4);
    uint2 hi, lo;
    hi.x = (P.x & 0xFFFFu) | (P.y << 16);
    hi.y = (P.z & 0xFFFFu) | (P.w << 16);
    lo.x = (P.x >> 16) | (P.y & 0xFFFF0000u);
    lo.y = (P.z >> 16) | (P.w & 0xFFFF0000u);
    *(uint2*)((ten ? pTh : tTh) + v * 136 + 4 * q4) = hi;
    *(uint2*)((ten ? pTl : tTl) + v * 136 + 4 * q4) = lo;
  }
  __syncthreads();
  f32x4 accS[5];
#pragma unroll
  for (int it = 0; it < 5; ++it) accS[it] = zero;
#pragma unroll
  for (int it = 0; it < 5; ++it) {
    const int t5 = wv + 8 * it;
    if (t5 < 36) {
      const int mt = t5 / 6, nt = t5 - 6 * (t5 / 6);
#pragma unroll
      for (int kk = 0; kk < 4; ++kk) {
        const int ao = (16 * mt + lr) * 136 + kk * 32 + 8 * lq;
        const int bo = (16 * nt + lr) * 136 + kk * 32 + 8 * lq;
        bf16x8 ah = *(const bf16x8*)&tTh[ao];
        bf16x8 al = *(const bf16x8*)&tTl[ao];
        bf16x8 bh = *(const bf16x8*)&pTh[bo];
        bf16x8 bl = *(const bf16x8*)&pTl[bo];
        accS[it] = MFMA16(ah, bh, accS[it]);
        accS[it] = MFMA16(ah, bl, accS[it]);
        accS[it] = MFMA16(al, bh, accS[it]);
      }
    }
  }
  __syncthreads();
  {
    float* esL = (float*)smem;
#pragma unroll
    for (int it = 0; it < 5; ++it) {
      const int t5 = wv + 8 * it;
      if (t5 < 36) {
        const int mt = t5 / 6, nt = t5 - 6 * (t5 / 6);
#pragma unroll
        for (int r = 0; r < 4; ++r)
          esL[(16 * nt + lr) * 101 + 16 * mt + 4 * lq + r] = accS[it][r];
      }
    }
  }
  __syncthreads();
  {
    float* esL = (float*)smem;
    if (tid < 96) {
      int v = tid; float m = -1e30f;
      for (int w2 = 0; w2 < 90; ++w2) m = fmaxf(m, esL[v * 101 + w2]);
      float s = 0.f;
      for (int w2 = 0; w2 < 90; ++w2) s += __expf(esL[v * 101 + w2] - m);
      st[v] = m; st[128 + v] = 1.f / s;
    } else if (tid >= 128 && tid < 224) {
      int v = tid - 128; float m = -1e30f;
      for (int w2 = 0; w2 < 90; ++w2) m = fmaxf(m, esL[w2 * 101 + v]);
      float s = 0.f;
      for (int w2 = 0; w2 < 90; ++w2) s += __expf(esL[w2 * 101 + v] - m);
      st[256 + v] = m; st[384 + v] = 1.f / s;
    }
  }
  __syncthreads();
  {
    float* esL = (float*)smem;
    for (int d = tid; d < 4608; d += 512) {
      int w2 = d / 48, vp = d - 48 * (d / 48);
      int v0 = 2 * vp, v1 = v0 + 1;
      float a0 = __expf(esL[v0 * 101 + w2] - st[v0]) * st[128 + v0];
      float a1 = __expf(esL[v1 * 101 + w2] - st[v1]) * st[128 + v1];
      S1[d] = packbf2(a0, a1);
      float b0 = __expf(esL[w2 * 101 + v0] - st[256 + v0]) * st[384 + v0];
      float b1 = __expf(esL[w2 * 101 + v1] - st[256 + v1]) * st[384 + v1];
      S2[d] = packbf2(b0, b1);
    }
  }
}

// ---------------- K3: r9 structure (measured best, ~145 us) ----------------
// smem: areaA [0,26624) = gT [96][136] then ZT [96][136]; areaB [26624,53248) = Tb [128][104]
__global__ __launch_bounds__(256) void k3_out(
    const float* __restrict__ x1, const float* __restrict__ x2,
    const u16* __restrict__ At1g, const u16* __restrict__ At2g,
    const u16* __restrict__ wW, const float* __restrict__ bW,
    const float* __restrict__ m1t, const float* __restrict__ x2cm, const float* __restrict__ x1am,
    float* __restrict__ out)
{
  __shared__ __align__(16) char smem[53248];
  u16* gT = (u16*)smem;                    // [96][136]
  u16* ZT = (u16*)smem;                    // overlays gT after T-pass
  u16* Tb = (u16*)(smem + 26624);          // [128][104]
  const int b = blockIdx.x, tid = threadIdx.x;
  const int l = tid & 63, wv = tid >> 6, lr = l & 15, lq = l >> 4;
  const f32x4 zero = {0.f, 0.f, 0.f, 0.f};

  float* out1 = out + (size_t)b * 23040;
  float* out2 = out + (size_t)23040 * 1024 + (size_t)b * 23040;
  const u16* g1s = (const u16*)out1;
  const u16* g2s = (const u16*)out2;
  const u16* As1 = (const u16*)out2 + 36864;
  const u16* As2 = (const u16*)out1 + 36864;

  auto phase = [&](const u16* __restrict__ gsrc, const u16* __restrict__ At,
                   const u16* __restrict__ AsT, const float* __restrict__ xres,
                   float* __restrict__ dst, bool modeA) {
    for (int i = tid; i < 1536; i += 256) {
      int v = i >> 4, hh = i & 15;
      *(uint4*)&gT[v * 136 + 8 * hh] = ((const uint4*)gsrc)[i];
    }
    __syncthreads();
#pragma unroll
    for (int ni = 0; ni < 2; ++ni) {
      const int nt = 2 * wv + ni;
      f32x4 acc[6];
#pragma unroll
      for (int i = 0; i < 6; ++i) acc[i] = zero;
#pragma unroll
      for (int kk = 0; kk < 4; ++kk) {
        bf16x8 bb = *(const bf16x8*)(At + (16 * nt + lr) * 128 + kk * 32 + 8 * lq);
#pragma unroll
        for (int mt = 0; mt < 6; ++mt) {
          bf16x8 a = *(const bf16x8*)&gT[(16 * mt + lr) * 136 + kk * 32 + 8 * lq];
          acc[mt] = MFMA16(a, bb, acc[mt]);
        }
      }
#pragma unroll
      for (int mt = 0; mt < 6; ++mt) {
        uint2 pk;
        pk.x = packbf2(acc[mt][0], acc[mt][1]);
        pk.y = packbf2(acc[mt][2], acc[mt][3]);
        *(uint2*)&Tb[(16 * nt + lr) * 104 + 16 * mt + 4 * lq] = pk;
      }
    }
    __syncthreads();   // all gT reads complete -> areaA reusable as ZT
    {
      f32x4 acc[2][6];
#pragma unroll
      for (int i = 0; i < 2; ++i)
#pragma unroll
        for (int j = 0; j < 6; ++j) acc[i][j] = zero;
#pragma unroll
      for (int kk = 0; kk < 3; ++kk) {
        bf16x8 a0 = *(const bf16x8*)&Tb[(16 * (2 * wv) + lr) * 104 + kk * 32 + 8 * lq];
        bf16x8 a1 = *(const bf16x8*)&Tb[(16 * (2 * wv + 1) + lr) * 104 + kk * 32 + 8 * lq];
#pragma unroll
        for (int nt = 0; nt < 6; ++nt) {
          bf16x8 bb = *(const bf16x8*)(AsT + (16 * nt + lr) * 96 + kk * 32 + 8 * lq);
          acc[0][nt] = MFMA16(a0, bb, acc[0][nt]);
          acc[1][nt] = MFMA16(a1, bb, acc[1][nt]);
        }
      }
#pragma unroll
      for (int mi = 0; mi < 2; ++mi) {
        const int mt = 2 * wv + mi;
#pragma unroll
        for (int nt = 0; nt < 6; ++nt) {
          uint2 pk;
          pk.x = packbf2(acc[mi][nt][0], acc[mi][nt][1]);
          pk.y = packbf2(acc[mi][nt][2], acc[mi][nt][3]);
          *(uint2*)&ZT[(16 * nt + lr) * 136 + 16 * mt + 4 * lq] = pk;
        }
      }
    }
    __syncthreads();
    const float am = modeA ? 0.f : x1am[b];
#pragma unroll
    for (int mi = 0; mi < 4; ++mi) {
      const int mt = 4 * wv + mi;
      f32x4 acc[6];
#pragma unroll
      for (int i = 0; i < 6; ++i) acc[i] = zero;
#pragma unroll
      for (int kk = 0; kk < 4; ++kk) {
        bf16x8 a = *(const bf16x8*)(wW + (16 * mt + lr) * 128 + kk * 32 + 8 * lq);
#pragma unroll
        for (int nt = 0; nt < 6; ++nt) {
          bf16x8 bb = *(const bf16x8*)&ZT[(16 * nt + lr) * 136 + kk * 32 + 8 * lq];
          acc[nt] = MFMA16(a, bb, acc[nt]);
        }
      }
      const int c0 = 16 * mt + 4 * lq;
      const float4 bw4 = *(const float4*)(bW + c0);
      float bwA[4] = {bw4.x, bw4.y, bw4.z, bw4.w};
      float mA[4] = {0.f, 0.f, 0.f, 0.f};
      if (modeA) {
        const float4 m4 = *(const float4*)(m1t + b * 256 + c0);
        mA[0] = m4.x; mA[1] = m4.y; mA[2] = m4.z; mA[3] = m4.w;
      }
#pragma unroll
      for (int nt = 0; nt < 6; ++nt) {
        const int v = 16 * nt + lr;
        if (v < 90) {
          const float addv = modeA ? 0.f : (am + x2cm[b * 96 + v]);
#pragma unroll
          for (int r = 0; r < 4; ++r) {
            const int c = c0 + r;
            const float extra = modeA ? mA[r] : addv;
            dst[c * 90 + v] = xres[c * 90 + v] + acc[nt][r] + bwA[r] + extra;
          }
        }
      }
    }
    __syncthreads();   // all ZT reads done before next phase restages gT
  };

  phase(g2s, At1g + (size_t)b * 16384, As1, x2 + (size_t)b * 23040, out2, true);
  phase(g1s, At2g + (size_t)b * 16384, As2, x1 + (size_t)b * 23040, out1, false);
}

} // namespace

extern "C" void kernel_launch(void* const* d_in, const int* in_sizes, int n_in,
                              void* d_out, int out_size, void* d_ws, size_t ws_size,
                              hipStream_t stream)
{
  (void)in_sizes; (void)n_in; (void)out_size; (void)ws_size;
  const float* x1  = (const float*)d_in[0];
  const float* x2  = (const float*)d_in[1];
  const float* gg  = (const float*)d_in[2];
  const float* gbe = (const float*)d_in[3];
  const float* gme = (const float*)d_in[4];
  const float* gva = (const float*)d_in[5];
  const float* gw  = (const float*)d_in[6];
  const float* gbi = (const float*)d_in[7];
  const float* tg  = (const float*)d_in[8];
  const float* tbe = (const float*)d_in[9];
  const float* tme = (const float*)d_in[10];
  const float* tva = (const float*)d_in[11];
  const float* tw  = (const float*)d_in[12];
  const float* tbi = (const float*)d_in[13];
  const float* pg  = (const float*)d_in[14];
  const float* pbe = (const float*)d_in[15];
  const float* pme = (const float*)d_in[16];
  const float* pva = (const float*)d_in[17];
  const float* pw  = (const float*)d_in[18];
  const float* pbi = (const float*)d_in[19];
  const float* Ww  = (const float*)d_in[20];
  const float* Wb  = (const float*)d_in[21];
  const float* Wg  = (const float*)d_in[22];
  const float* Wbe = (const float*)d_in[23];
  const float* Wme = (const float*)d_in[24];
  const float* Wva = (const float*)d_in[25];
  // d_in[26..33] (qt/ks/qs/kt) are dead: softmax over singleton axis == 1.

  float* out = (float*)d_out;
  unsigned char* W8 = (unsigned char*)d_ws;

  size_t off = 0;
  auto al = [&](size_t n) { size_t r = off; off += (n + 255) & ~(size_t)255; return r; };
  const size_t oWG  = al(65536);
  const size_t oWTh = al(65536), oWTl = al(65536);
  const size_t oWPh = al(65536), oWPl = al(65536);
  const size_t oWW  = al(65536);
  const size_t oBG = al(512), oBT = al(512), oBP = al(512), oBW = al(1024);
  const size_t oRM1 = al((size_t)B * 49152), oRM2 = al((size_t)B * 49152);
  const size_t oA1 = al((size_t)B * 32768), oA2 = al((size_t)B * 32768);
  const size_t oM1 = al((size_t)B * 1024), oXC = al((size_t)B * 384), oXA = al((size_t)B * 4);
  // total ~168.4 MB; thT_pk/phT_pk/As1/As2 live in unused d_out space.

  k0_fold<<<dim3(640), dim3(256), 0, stream>>>(
      gg, gbe, gme, gva, gw, gbi,
      tg, tbe, tme, tva, tw, tbi,
      pg, pbe, pme, pva, pw, pbi,
      Ww, Wb, Wg, Wbe, Wme, Wva,
      (u16*)(W8 + oWG), (float*)(W8 + oBG),
      (u16*)(W8 + oWTh), (u16*)(W8 + oWTl), (float*)(W8 + oBT),
      (u16*)(W8 + oWPh), (u16*)(W8 + oWPl), (float*)(W8 + oBP),
      (u16*)(W8 + oWW), (float*)(W8 + oBW));

  k1_conv<<<dim3(B), dim3(512), 0, stream>>>(
      x1, x2,
      (const u16*)(W8 + oWG), (const float*)(W8 + oBG),
      (const u16*)(W8 + oWTh), (const u16*)(W8 + oWTl), (const float*)(W8 + oBT),
      (const u16*)(W8 + oWPh), (const u16*)(W8 + oWPl), (const float*)(W8 + oBP),
      (u32*)(W8 + oRM1), (u32*)(W8 + oRM2),
      (u16*)out,
      (float*)(W8 + oM1), (float*)(W8 + oXC), (float*)(W8 + oXA));

  k2_attn<<<dim3(B), dim3(512), 0, stream>>>(
      (const u32*)(W8 + oRM1), (const u32*)(W8 + oRM2),
      (u16*)out,
      (u16*)(W8 + oA1), (u16*)(W8 + oA2));

  k3_out<<<dim3(B), dim3(256), 0, stream>>>(
      x1, x2,
      (const u16*)(W8 + oA1), (const u16*)(W8 + oA2),
      (const u16*)(W8 + oWW), (const float*)(W8 + oBW),
      (const float*)(W8 + oM1), (const float*)(W8 + oXC), (const float*)(W8 + oXA),
      out);
}